// Round 1
// baseline (364.487 us; speedup 1.0000x reference)
//
#include <hip/hip_runtime.h>
#include <hip/hip_bf16.h>
#include <math.h>

#define NE 8
#define TOPK 2
#define HD 1024
#define FD 4096
#define NTOK 4096
#define NASSIGN 8192
#define CAP 1024

#define BM 128
#define BN 128
#define BK 32

typedef __attribute__((ext_vector_type(8))) short short8;
typedef __attribute__((ext_vector_type(4))) float f32x4;
typedef __attribute__((ext_vector_type(4))) unsigned short us4;
typedef __attribute__((ext_vector_type(4))) unsigned int u32x4;

__device__ __forceinline__ unsigned short f2bf(float f) {
  unsigned u = __float_as_uint(f);
  u += 0x7fffu + ((u >> 16) & 1u);
  return (unsigned short)(u >> 16);
}

__device__ __forceinline__ void load_lds16(const void* g, void* l) {
  __builtin_amdgcn_global_load_lds((const __attribute__((address_space(1))) void*)g,
                                   (__attribute__((address_space(3))) void*)l, 16, 0, 0);
}

// ---------------- transpose + fp32->bf16 convert: W[R][C] -> Wt[C][R] ----------------
__global__ __launch_bounds__(256)
void transpose_convert(const float* __restrict__ W, unsigned short* __restrict__ Wt,
                       int R, int C) {
  __shared__ float tile[64][65];
  int e = blockIdx.z;
  W  += (size_t)e * R * C;
  Wt += (size_t)e * R * C;
  int c0 = blockIdx.x * 64, r0 = blockIdx.y * 64;
  int tx = threadIdx.x & 15, ty = threadIdx.x >> 4;
#pragma unroll
  for (int i = 0; i < 4; ++i) {
    f32x4 v = *(const f32x4*)(W + (size_t)(r0 + ty + i * 16) * C + c0 + tx * 4);
    tile[ty + i * 16][tx * 4 + 0] = v.x;
    tile[ty + i * 16][tx * 4 + 1] = v.y;
    tile[ty + i * 16][tx * 4 + 2] = v.z;
    tile[ty + i * 16][tx * 4 + 3] = v.w;
  }
  __syncthreads();
#pragma unroll
  for (int i = 0; i < 4; ++i) {
    int c = ty + i * 16;
    us4 o;
    o.x = f2bf(tile[tx * 4 + 0][c]);
    o.y = f2bf(tile[tx * 4 + 1][c]);
    o.z = f2bf(tile[tx * 4 + 2][c]);
    o.w = f2bf(tile[tx * 4 + 3][c]);
    *(us4*)(Wt + (size_t)(c0 + c) * R + r0 + tx * 4) = o;
  }
}

// ---------------- routing: stable counting sort metadata ----------------
// rankA[a] = # of assignments a' < a with same expert (== pos within expert bin)
// srcTok[e*CAP + r] = token index feeding buf[e][r]   (only for r < CAP)
// counts[e] = tokens routed to expert e (may exceed CAP)
__global__ __launch_bounds__(1024)
void routing_kernel(const int* __restrict__ te, int* __restrict__ rankA,
                    int* __restrict__ srcTok, int* __restrict__ counts) {
  __shared__ uint4 pref[1024];
  int t = threadIdx.x;
  int myTe[8];
  unsigned lc[4] = {0, 0, 0, 0};
#pragma unroll
  for (int j = 0; j < 8; ++j) {
    int ee = te[t * 8 + j];
    myTe[j] = ee;
    lc[ee >> 1] += 1u << ((ee & 1) * 16);
  }
  uint4 inc;
  inc.x = lc[0]; inc.y = lc[1]; inc.z = lc[2]; inc.w = lc[3];
  pref[t] = inc;
  __syncthreads();
  for (int d = 1; d < 1024; d <<= 1) {
    uint4 add;
    bool has = (t >= d);
    if (has) add = pref[t - d];
    __syncthreads();
    if (has) {
      inc.x += add.x; inc.y += add.y; inc.z += add.z; inc.w += add.w;
      pref[t] = inc;
    }
    __syncthreads();
  }
  uint4 tot = pref[1023];
  unsigned ex[4] = {inc.x - lc[0], inc.y - lc[1], inc.z - lc[2], inc.w - lc[3]};
  int run[8];
#pragma unroll
  for (int eidx = 0; eidx < 8; ++eidx)
    run[eidx] = (ex[eidx >> 1] >> ((eidx & 1) * 16)) & 0xffff;
#pragma unroll
  for (int j = 0; j < 8; ++j) {
    int ee = myTe[j];
    int r = run[ee]++;
    rankA[t * 8 + j] = r;
    if (r < CAP) srcTok[ee * CAP + r] = (t * 8 + j) >> 1;  // token = a / TOPK
  }
  if (t < 8) {
    unsigned tt[4] = {tot.x, tot.y, tot.z, tot.w};
    counts[t] = (tt[t >> 1] >> ((t & 1) * 16)) & 0xffff;
  }
}

// ---------------- gather x rows into bf16 buf[E][CAP][HD], zero pad ----------------
__global__ __launch_bounds__(128)
void gather_kernel(const float* __restrict__ x, const int* __restrict__ srcTok,
                   const int* __restrict__ counts, unsigned short* __restrict__ buf) {
  int row = blockIdx.x;          // e*CAP + c
  int e = row >> 10;
  int c = row & (CAP - 1);
  int t = threadIdx.x;           // 128 threads, 8 elems each
  unsigned short* dst = buf + (size_t)row * HD + t * 8;
  if (c < counts[e]) {
    const float* src = x + (size_t)srcTok[row] * HD + t * 8;
    f32x4 v0 = *(const f32x4*)src;
    f32x4 v1 = *(const f32x4*)(src + 4);
    u32x4 o;
    o.x = f2bf(v0.x) | ((unsigned)f2bf(v0.y) << 16);
    o.y = f2bf(v0.z) | ((unsigned)f2bf(v0.w) << 16);
    o.z = f2bf(v1.x) | ((unsigned)f2bf(v1.y) << 16);
    o.w = f2bf(v1.z) | ((unsigned)f2bf(v1.w) << 16);
    *(u32x4*)dst = o;
  } else {
    u32x4 z = {0, 0, 0, 0};
    *(u32x4*)dst = z;
  }
}

// ---------------- batched GEMM, A[M][K] @ Bt[N][K]^T -> C[M][N], per expert ----------
// DO_GELU=1: exact gelu epilogue, bf16 output. DO_GELU=0: fp32 output.
template <int DO_GELU>
__global__ __launch_bounds__(256)
void gemm_bt(const unsigned short* __restrict__ Ab, const unsigned short* __restrict__ Bb,
             void* __restrict__ Cv, int M, int N, int K) {
  int e = blockIdx.z;
  const unsigned short* A  = Ab + (size_t)e * M * K;
  const unsigned short* Bt = Bb + (size_t)e * N * K;
  int bm = blockIdx.x * BM;
  int bn = blockIdx.y * BN;
  __shared__ unsigned short As[BM * BK];
  __shared__ unsigned short Bs[BN * BK];
  int tid = threadIdx.x;
  int lane = tid & 63;
  int w = tid >> 6;
  int wm = (w >> 1) * 64, wn = (w & 1) * 64;
  int l15 = lane & 15, lk = (lane >> 4) * 8;
  f32x4 acc[4][4] = {};
  const unsigned short* ga = A + (size_t)bm * K;
  const unsigned short* gb = Bt + (size_t)bn * K;
  for (int k0 = 0; k0 < K; k0 += BK) {
#pragma unroll
    for (int it = 0; it < 2; ++it) {
      int eidx = (it * 256 + tid) * 8;         // bf16-element offset within 128x32 tile
      int r = eidx >> 5, kk = eidx & 31;
      load_lds16(ga + (size_t)r * K + k0 + kk, As + eidx);
      load_lds16(gb + (size_t)r * K + k0 + kk, Bs + eidx);
    }
    __syncthreads();
    short8 af[4], bfr[4];
#pragma unroll
    for (int m = 0; m < 4; ++m)
      af[m] = *(const short8*)(As + (wm + m * 16 + l15) * BK + lk);
#pragma unroll
    for (int n = 0; n < 4; ++n)
      bfr[n] = *(const short8*)(Bs + (wn + n * 16 + l15) * BK + lk);
#pragma unroll
    for (int m = 0; m < 4; ++m)
#pragma unroll
      for (int n = 0; n < 4; ++n)
        acc[m][n] = __builtin_amdgcn_mfma_f32_16x16x32_bf16(af[m], bfr[n], acc[m][n], 0, 0, 0);
    __syncthreads();
  }
  int r0 = bm + wm + (lane >> 4) * 4;
  int c0 = bn + wn + l15;
  if (DO_GELU) {
    unsigned short* Cb = (unsigned short*)Cv + (size_t)e * M * N;
#pragma unroll
    for (int m = 0; m < 4; ++m)
#pragma unroll
      for (int n = 0; n < 4; ++n)
#pragma unroll
        for (int j = 0; j < 4; ++j) {
          float v = acc[m][n][j];
          float g = 0.5f * v * (1.0f + erff(v * 0.70710678118654752f));
          Cb[(size_t)(r0 + m * 16 + j) * N + (c0 + n * 16)] = f2bf(g);
        }
  } else {
    float* Cf = (float*)Cv + (size_t)e * M * N;
#pragma unroll
    for (int m = 0; m < 4; ++m)
#pragma unroll
      for (int n = 0; n < 4; ++n)
#pragma unroll
        for (int j = 0; j < 4; ++j)
          Cf[(size_t)(r0 + m * 16 + j) * N + (c0 + n * 16)] = acc[m][n][j];
  }
}

// ---------------- scatter: out[t] = sum_k w[t,k]*y[e,r] + bias ----------------
__global__ __launch_bounds__(128)
void scatter_kernel(const float* __restrict__ y, const int* __restrict__ te,
                    const int* __restrict__ rankA, const float* __restrict__ ew,
                    const float* __restrict__ bias, float* __restrict__ out) {
  int tk = blockIdx.x;
  int t = threadIdx.x;
  f32x4 a0 = *(const f32x4*)(bias + t * 8);
  f32x4 a1 = *(const f32x4*)(bias + t * 8 + 4);
#pragma unroll
  for (int k = 0; k < TOPK; ++k) {
    int a = tk * TOPK + k;
    int r = rankA[a];
    if (r < CAP) {
      float wgt = ew[a];
      const float* yr = y + ((size_t)te[a] * CAP + r) * HD + t * 8;
      f32x4 v0 = *(const f32x4*)yr;
      f32x4 v1 = *(const f32x4*)(yr + 4);
      a0 += wgt * v0;
      a1 += wgt * v1;
    }
  }
  float* o = out + (size_t)tk * HD + t * 8;
  *(f32x4*)o = a0;
  *(f32x4*)(o + 4) = a1;
}

extern "C" void kernel_launch(void* const* d_in, const int* in_sizes, int n_in,
                              void* d_out, int out_size, void* d_ws, size_t ws_size,
                              hipStream_t stream) {
  const float* x    = (const float*)d_in[0];
  // d_in[1] = scores (unused by reference compute)
  const float* ew   = (const float*)d_in[2];
  const int*   te   = (const int*)d_in[3];
  const float* w1   = (const float*)d_in[4];
  const float* w2   = (const float*)d_in[5];
  const float* bias = (const float*)d_in[6];
  float* out = (float*)d_out;

  unsigned short* w1t  = (unsigned short*)d_ws;                 // [E][F][H] bf16  64MB
  unsigned short* w2t  = w1t + (size_t)NE * HD * FD;            // [E][H][F] bf16  64MB
  unsigned short* buf  = w2t + (size_t)NE * HD * FD;            // [E][CAP][H]     16MB
  unsigned short* hbuf = buf + (size_t)NE * CAP * HD;           // [E][CAP][F]     64MB
  float*          ybuf = (float*)(hbuf + (size_t)NE * CAP * FD);// [E][CAP][H] f32 32MB
  int* rankA  = (int*)(ybuf + (size_t)NE * CAP * HD);
  int* srcTok = rankA + NASSIGN;
  int* counts = srcTok + NE * CAP;

  transpose_convert<<<dim3(FD / 64, HD / 64, NE), 256, 0, stream>>>(w1, w1t, HD, FD);
  transpose_convert<<<dim3(HD / 64, FD / 64, NE), 256, 0, stream>>>(w2, w2t, FD, HD);
  routing_kernel<<<1, 1024, 0, stream>>>(te, rankA, srcTok, counts);
  gather_kernel<<<NE * CAP, 128, 0, stream>>>(x, srcTok, counts, buf);
  gemm_bt<1><<<dim3(CAP / BM, FD / BN, NE), 256, 0, stream>>>(buf, w1t, (void*)hbuf, CAP, FD, HD);
  gemm_bt<0><<<dim3(CAP / BM, HD / BN, NE), 256, 0, stream>>>(hbuf, w2t, (void*)ybuf, CAP, HD, FD);
  scatter_kernel<<<NTOK, 128, 0, stream>>>(ybuf, te, rankA, ew, bias, out);
}

// Round 2
// 278.397 us; speedup vs baseline: 1.3092x; 1.3092x over previous
//
#include <hip/hip_runtime.h>
#include <hip/hip_bf16.h>
#include <math.h>

#define NE 8
#define TOPK 2
#define HD 1024
#define FD 4096
#define NTOK 4096
#define NASSIGN 8192
#define CAP 1024

typedef __attribute__((ext_vector_type(8))) short short8;
typedef __attribute__((ext_vector_type(4))) float f32x4;
typedef __attribute__((ext_vector_type(4))) unsigned short us4;
typedef __attribute__((ext_vector_type(4))) unsigned int u32x4;

__device__ __forceinline__ unsigned short f2bf(float f) {
  unsigned u = __float_as_uint(f);
  u += 0x7fffu + ((u >> 16) & 1u);
  return (unsigned short)(u >> 16);
}

__device__ __forceinline__ void load_lds16(const void* g, void* l) {
  __builtin_amdgcn_global_load_lds((const __attribute__((address_space(1))) void*)g,
                                   (__attribute__((address_space(3))) void*)l, 16, 0, 0);
}

// XOR swizzle: permutes 16B blocks within a row-pair group; involution; bits>=6 unchanged.
__device__ __forceinline__ unsigned swz(unsigned b) {
  return b ^ (((b >> 7) & 3u) << 4);
}

// ---------------- transpose + fp32->bf16 convert: W[R][C] -> Wt[C][R] ----------------
__global__ __launch_bounds__(256)
void transpose_convert(const float* __restrict__ W, unsigned short* __restrict__ Wt,
                       int R, int C) {
  __shared__ float tile[64][65];
  int e = blockIdx.z;
  W  += (size_t)e * R * C;
  Wt += (size_t)e * R * C;
  int c0 = blockIdx.x * 64, r0 = blockIdx.y * 64;
  int tx = threadIdx.x & 15, ty = threadIdx.x >> 4;
#pragma unroll
  for (int i = 0; i < 4; ++i) {
    f32x4 v = *(const f32x4*)(W + (size_t)(r0 + ty + i * 16) * C + c0 + tx * 4);
    tile[ty + i * 16][tx * 4 + 0] = v.x;
    tile[ty + i * 16][tx * 4 + 1] = v.y;
    tile[ty + i * 16][tx * 4 + 2] = v.z;
    tile[ty + i * 16][tx * 4 + 3] = v.w;
  }
  __syncthreads();
#pragma unroll
  for (int i = 0; i < 4; ++i) {
    int c = ty + i * 16;
    us4 o;
    o.x = f2bf(tile[tx * 4 + 0][c]);
    o.y = f2bf(tile[tx * 4 + 1][c]);
    o.z = f2bf(tile[tx * 4 + 2][c]);
    o.w = f2bf(tile[tx * 4 + 3][c]);
    *(us4*)(Wt + (size_t)(c0 + c) * R + r0 + tx * 4) = o;
  }
}

// ---------------- routing: stable counting sort metadata ----------------
__global__ __launch_bounds__(1024)
void routing_kernel(const int* __restrict__ te, int* __restrict__ rankA,
                    int* __restrict__ srcTok, int* __restrict__ counts) {
  __shared__ uint4 pref[1024];
  int t = threadIdx.x;
  int myTe[8];
  unsigned lc[4] = {0, 0, 0, 0};
#pragma unroll
  for (int j = 0; j < 8; ++j) {
    int ee = te[t * 8 + j];
    myTe[j] = ee;
    lc[ee >> 1] += 1u << ((ee & 1) * 16);
  }
  uint4 inc;
  inc.x = lc[0]; inc.y = lc[1]; inc.z = lc[2]; inc.w = lc[3];
  pref[t] = inc;
  __syncthreads();
  for (int d = 1; d < 1024; d <<= 1) {
    uint4 add;
    bool has = (t >= d);
    if (has) add = pref[t - d];
    __syncthreads();
    if (has) {
      inc.x += add.x; inc.y += add.y; inc.z += add.z; inc.w += add.w;
      pref[t] = inc;
    }
    __syncthreads();
  }
  uint4 tot = pref[1023];
  unsigned ex[4] = {inc.x - lc[0], inc.y - lc[1], inc.z - lc[2], inc.w - lc[3]};
  int run[8];
#pragma unroll
  for (int eidx = 0; eidx < 8; ++eidx)
    run[eidx] = (ex[eidx >> 1] >> ((eidx & 1) * 16)) & 0xffff;
#pragma unroll
  for (int j = 0; j < 8; ++j) {
    int ee = myTe[j];
    int r = run[ee]++;
    rankA[t * 8 + j] = r;
    if (r < CAP) srcTok[ee * CAP + r] = (t * 8 + j) >> 1;
  }
  if (t < 8) {
    unsigned tt[4] = {tot.x, tot.y, tot.z, tot.w};
    counts[t] = (tt[t >> 1] >> ((t & 1) * 16)) & 0xffff;
  }
}

// ---------------- gather x rows into bf16 buf[E][CAP][HD], zero pad ----------------
__global__ __launch_bounds__(128)
void gather_kernel(const float* __restrict__ x, const int* __restrict__ srcTok,
                   const int* __restrict__ counts, unsigned short* __restrict__ buf) {
  int row = blockIdx.x;
  int e = row >> 10;
  int c = row & (CAP - 1);
  int t = threadIdx.x;
  unsigned short* dst = buf + (size_t)row * HD + t * 8;
  if (c < counts[e]) {
    const float* src = x + (size_t)srcTok[row] * HD + t * 8;
    f32x4 v0 = *(const f32x4*)src;
    f32x4 v1 = *(const f32x4*)(src + 4);
    u32x4 o;
    o.x = f2bf(v0.x) | ((unsigned)f2bf(v0.y) << 16);
    o.y = f2bf(v0.z) | ((unsigned)f2bf(v0.w) << 16);
    o.z = f2bf(v1.x) | ((unsigned)f2bf(v1.y) << 16);
    o.w = f2bf(v1.z) | ((unsigned)f2bf(v1.w) << 16);
    *(u32x4*)dst = o;
  } else {
    u32x4 z = {0, 0, 0, 0};
    *(u32x4*)dst = z;
  }
}

// ---------------- 256x256 ring-4 deep-pipelined batched GEMM ----------------
// A[e][CAP][KTOT] (bf16, row-major), Bt[e][NDIM][KTOT] (bf16, row-major = B^T).
// C = A @ Bt^T. 8 waves (2M x 4N), per-wave 128x64, BK=32, 4 LDS buffers,
// counted vmcnt(8) (3 tiles in flight), raw s_barrier, setprio around MFMA.
template <int KTOT, int NDIM, int DO_GELU, int KSPLIT>
__global__ __launch_bounds__(512, 2)
void gemm256(const unsigned short* __restrict__ Ab, const unsigned short* __restrict__ Bb,
             void* __restrict__ Cv) {
  constexpr int KLOC = KTOT / KSPLIT;
  constexpr int NT = KLOC / 32;              // K-tiles per block
  constexpr int GX = CAP / 256;              // M blocks
  constexpr int GY = NDIM / 256;             // N blocks
  constexpr int NWG = GX * GY * NE * KSPLIT;
  __shared__ char smem[4 * 32768];           // 4 bufs x (A 16KB + B 16KB)

  // XCD-aware bijective swizzle (NWG % 8 == 0)
  int orig = blockIdx.x;
  int wg = (orig & 7) * (NWG / 8) + (orig >> 3);
  int bx = wg % GX;
  int by = (wg / GX) % GY;
  int zz = wg / (GX * GY);
  int ks = zz % KSPLIT;
  int e  = zz / KSPLIT;

  const unsigned short* A  = Ab + (size_t)e * CAP * KTOT;
  const unsigned short* Bt = Bb + (size_t)e * NDIM * KTOT;
  int bm = bx * 256, bn = by * 256;
  int kbase = ks * KLOC;

  int tid = threadIdx.x;
  int lane = tid & 63;
  int w = tid >> 6;
  int wr = w >> 2, wc = w & 3;
  int l15 = lane & 15, lq = lane >> 4;

  // ds_read byte offsets within a 16KB tile region (swizzled)
  unsigned offA[8], offB[4];
#pragma unroll
  for (int m = 0; m < 8; ++m)
    offA[m] = swz((unsigned)((wr * 128 + m * 16 + l15) * 64 + lq * 16));
#pragma unroll
  for (int n = 0; n < 4; ++n)
    offB[n] = swz((unsigned)((wc * 64 + n * 16 + l15) * 64 + lq * 16));

  // staging: 2 loads/thread per operand per tile; LDS dest linear, source pre-swizzled
  const char* srcA[2]; const char* srcB[2];
  unsigned ldsOffA[2], ldsOffB[2];
#pragma unroll
  for (int i = 0; i < 2; ++i) {
    int idx = i * 512 + tid;
    int row = idx >> 2;                                 // tile row this 16B block lands in
    unsigned kb = (unsigned)((idx & 3) * 16) ^ ((((unsigned)row >> 1) & 3u) << 4);
    srcA[i] = (const char*)A  + ((size_t)(bm + row) * KTOT + kbase) * 2 + kb;
    srcB[i] = (const char*)Bt + ((size_t)(bn + row) * KTOT + kbase) * 2 + kb;
    ldsOffA[i] = (unsigned)idx * 16;
    ldsOffB[i] = 16384u + (unsigned)idx * 16;
  }

  // prologue: stage tiles 0,1,2 into bufs 0,1,2
#pragma unroll
  for (int tt = 0; tt < 3; ++tt) {
    char* db = smem + tt * 32768;
#pragma unroll
    for (int i = 0; i < 2; ++i) {
      load_lds16(srcA[i] + tt * 64, db + ldsOffA[i]);
      load_lds16(srcB[i] + tt * 64, db + ldsOffB[i]);
    }
  }
  srcA[0] += 192; srcA[1] += 192; srcB[0] += 192; srcB[1] += 192;
  asm volatile("s_waitcnt vmcnt(8)\ns_barrier" ::: "memory");

  f32x4 acc[8][4] = {};

  auto step = [&](int t, int bufi) {
    if (t + 3 < NT) {                         // stage tile t+3 -> buf (bufi+3)&3
      char* db = smem + ((bufi + 3) & 3) * 32768;
#pragma unroll
      for (int i = 0; i < 2; ++i) {
        load_lds16(srcA[i], db + ldsOffA[i]);
        load_lds16(srcB[i], db + ldsOffB[i]);
      }
      srcA[0] += 64; srcA[1] += 64; srcB[0] += 64; srcB[1] += 64;
    }
    const char* rb = smem + bufi * 32768;
    short8 af[8], bf[4];
#pragma unroll
    for (int m = 0; m < 8; ++m) af[m] = *(const short8*)(rb + offA[m]);
#pragma unroll
    for (int n = 0; n < 4; ++n) bf[n] = *(const short8*)(rb + 16384 + offB[n]);
    asm volatile("s_waitcnt lgkmcnt(0)" ::: "memory");
    __builtin_amdgcn_sched_barrier(0);
    __builtin_amdgcn_s_setprio(1);
#pragma unroll
    for (int m = 0; m < 8; ++m)
#pragma unroll
      for (int n = 0; n < 4; ++n)
        acc[m][n] = __builtin_amdgcn_mfma_f32_16x16x32_bf16(af[m], bf[n], acc[m][n], 0, 0, 0);
    __builtin_amdgcn_s_setprio(0);
    __builtin_amdgcn_sched_barrier(0);
    asm volatile("s_waitcnt vmcnt(8)\ns_barrier" ::: "memory");
  };

  for (int t = 0; t < NT; t += 4) {
    step(t + 0, 0);
    step(t + 1, 1);
    step(t + 2, 2);
    step(t + 3, 3);
  }

  // epilogue
  int r0 = bm + wr * 128 + lq * 4;
  int c0 = bn + wc * 64 + l15;
  if (DO_GELU) {
    unsigned short* C = (unsigned short*)Cv + (size_t)e * CAP * NDIM;
#pragma unroll
    for (int m = 0; m < 8; ++m)
#pragma unroll
      for (int n = 0; n < 4; ++n)
#pragma unroll
        for (int j = 0; j < 4; ++j) {
          float v = acc[m][n][j];
          float y = 0.7978845608028654f * (v + 0.044715f * v * v * v);
          float g = v / (1.0f + __expf(-2.0f * y));   // v * sigmoid(2y) = tanh-gelu
          C[(size_t)(r0 + m * 16 + j) * NDIM + (c0 + n * 16)] = f2bf(g);
        }
  } else {
    float* C = (float*)Cv + ((size_t)ks * NE + e) * CAP * NDIM;
#pragma unroll
    for (int m = 0; m < 8; ++m)
#pragma unroll
      for (int n = 0; n < 4; ++n)
#pragma unroll
        for (int j = 0; j < 4; ++j)
          C[(size_t)(r0 + m * 16 + j) * NDIM + (c0 + n * 16)] = acc[m][n][j];
  }
}

// ---------------- scatter: out[t] = sum_k w[t,k]*(y0[e,r]+y1[e,r]) + bias ----------------
__global__ __launch_bounds__(128)
void scatter_kernel(const float* __restrict__ y, const int* __restrict__ te,
                    const int* __restrict__ rankA, const float* __restrict__ ew,
                    const float* __restrict__ bias, float* __restrict__ out) {
  int tk = blockIdx.x;
  int t = threadIdx.x;
  f32x4 a0 = *(const f32x4*)(bias + t * 8);
  f32x4 a1 = *(const f32x4*)(bias + t * 8 + 4);
#pragma unroll
  for (int k = 0; k < TOPK; ++k) {
    int a = tk * TOPK + k;
    int r = rankA[a];
    if (r < CAP) {
      float wgt = ew[a];
      size_t rowoff = ((size_t)te[a] * CAP + r) * HD + t * 8;
      const float* y0 = y + rowoff;
      const float* y1 = y + (size_t)NE * CAP * HD + rowoff;
      f32x4 v0 = *(const f32x4*)y0 + *(const f32x4*)y1;
      f32x4 v1 = *(const f32x4*)(y0 + 4) + *(const f32x4*)(y1 + 4);
      a0 += wgt * v0;
      a1 += wgt * v1;
    }
  }
  float* o = out + (size_t)tk * HD + t * 8;
  *(f32x4*)o = a0;
  *(f32x4*)(o + 4) = a1;
}

extern "C" void kernel_launch(void* const* d_in, const int* in_sizes, int n_in,
                              void* d_out, int out_size, void* d_ws, size_t ws_size,
                              hipStream_t stream) {
  const float* x    = (const float*)d_in[0];
  const float* ew   = (const float*)d_in[2];
  const int*   te   = (const int*)d_in[3];
  const float* w1   = (const float*)d_in[4];
  const float* w2   = (const float*)d_in[5];
  const float* bias = (const float*)d_in[6];
  float* out = (float*)d_out;

  unsigned short* w1t  = (unsigned short*)d_ws;                 // [E][F][H] bf16  64MB
  unsigned short* w2t  = w1t + (size_t)NE * HD * FD;            // [E][H][F] bf16  64MB
  unsigned short* bufg = w2t + (size_t)NE * HD * FD;            // [E][CAP][H]     16MB
  unsigned short* hbuf = bufg + (size_t)NE * CAP * HD;          // [E][CAP][F]     64MB
  float*          ybuf = (float*)w1t;                           // alias: [2][E][CAP][H] f32 64MB
  int* rankA  = (int*)(hbuf + (size_t)NE * CAP * FD);
  int* srcTok = rankA + NASSIGN;
  int* counts = srcTok + NE * CAP;

  transpose_convert<<<dim3(FD / 64, HD / 64, NE), 256, 0, stream>>>(w1, w1t, HD, FD);
  transpose_convert<<<dim3(HD / 64, FD / 64, NE), 256, 0, stream>>>(w2, w2t, FD, HD);
  routing_kernel<<<1, 1024, 0, stream>>>(te, rankA, srcTok, counts);
  gather_kernel<<<NE * CAP, 128, 0, stream>>>(x, srcTok, counts, bufg);
  // GEMM1: [CAP,HD] @ [FD,HD]^T -> gelu -> bf16 hbuf ; 4*16*8 = 512 blocks
  gemm256<HD, FD, 1, 1><<<512, 512, 0, stream>>>(bufg, w1t, (void*)hbuf);
  // GEMM2: [CAP,FD] @ [HD,FD]^T -> fp32 partials (split-K=2) ; 4*4*8*2 = 256 blocks
  gemm256<FD, HD, 0, 2><<<256, 512, 0, stream>>>(hbuf, w2t, (void*)ybuf);
  scatter_kernel<<<NTOK, 128, 0, stream>>>(ybuf, te, rankA, ew, bias, out);
}

// Round 3
// 250.453 us; speedup vs baseline: 1.4553x; 1.1116x over previous
//
#include <hip/hip_runtime.h>
#include <hip/hip_bf16.h>
#include <math.h>

#define NE 8
#define TOPK 2
#define HD 1024
#define FD 4096
#define NTOK 4096
#define NASSIGN 8192
#define CAP 1024

typedef __attribute__((ext_vector_type(8))) short short8;
typedef __attribute__((ext_vector_type(4))) float f32x4;
typedef __attribute__((ext_vector_type(4))) unsigned short us4;
typedef __attribute__((ext_vector_type(4))) unsigned int u32x4;

__device__ __forceinline__ unsigned short f2bf(float f) {
  unsigned u = __float_as_uint(f);
  u += 0x7fffu + ((u >> 16) & 1u);
  return (unsigned short)(u >> 16);
}

__device__ __forceinline__ void load_lds16(const void* g, void* l) {
  __builtin_amdgcn_global_load_lds((const __attribute__((address_space(1))) void*)g,
                                   (__attribute__((address_space(3))) void*)l, 16, 0, 0);
}

// ---------------- transpose + fp32->bf16 convert: W[R][C] -> Wt[C][R] ----------------
__global__ __launch_bounds__(256)
void transpose_convert(const float* __restrict__ W, unsigned short* __restrict__ Wt,
                       int R, int C) {
  __shared__ float tile[64][65];
  int e = blockIdx.z;
  W  += (size_t)e * R * C;
  Wt += (size_t)e * R * C;
  int c0 = blockIdx.x * 64, r0 = blockIdx.y * 64;
  int tx = threadIdx.x & 15, ty = threadIdx.x >> 4;
#pragma unroll
  for (int i = 0; i < 4; ++i) {
    f32x4 v = *(const f32x4*)(W + (size_t)(r0 + ty + i * 16) * C + c0 + tx * 4);
    tile[ty + i * 16][tx * 4 + 0] = v.x;
    tile[ty + i * 16][tx * 4 + 1] = v.y;
    tile[ty + i * 16][tx * 4 + 2] = v.z;
    tile[ty + i * 16][tx * 4 + 3] = v.w;
  }
  __syncthreads();
#pragma unroll
  for (int i = 0; i < 4; ++i) {
    int c = ty + i * 16;
    us4 o;
    o.x = f2bf(tile[tx * 4 + 0][c]);
    o.y = f2bf(tile[tx * 4 + 1][c]);
    o.z = f2bf(tile[tx * 4 + 2][c]);
    o.w = f2bf(tile[tx * 4 + 3][c]);
    *(us4*)(Wt + (size_t)(c0 + c) * R + r0 + tx * 4) = o;
  }
}

// ---------------- routing: stable counting sort metadata ----------------
__global__ __launch_bounds__(1024)
void routing_kernel(const int* __restrict__ te, int* __restrict__ rankA,
                    int* __restrict__ srcTok, int* __restrict__ counts) {
  __shared__ uint4 pref[1024];
  int t = threadIdx.x;
  int myTe[8];
  unsigned lc[4] = {0, 0, 0, 0};
#pragma unroll
  for (int j = 0; j < 8; ++j) {
    int ee = te[t * 8 + j];
    myTe[j] = ee;
    lc[ee >> 1] += 1u << ((ee & 1) * 16);
  }
  uint4 inc;
  inc.x = lc[0]; inc.y = lc[1]; inc.z = lc[2]; inc.w = lc[3];
  pref[t] = inc;
  __syncthreads();
  for (int d = 1; d < 1024; d <<= 1) {
    uint4 add;
    bool has = (t >= d);
    if (has) add = pref[t - d];
    __syncthreads();
    if (has) {
      inc.x += add.x; inc.y += add.y; inc.z += add.z; inc.w += add.w;
      pref[t] = inc;
    }
    __syncthreads();
  }
  uint4 tot = pref[1023];
  unsigned ex[4] = {inc.x - lc[0], inc.y - lc[1], inc.z - lc[2], inc.w - lc[3]};
  int run[8];
#pragma unroll
  for (int eidx = 0; eidx < 8; ++eidx)
    run[eidx] = (ex[eidx >> 1] >> ((eidx & 1) * 16)) & 0xffff;
#pragma unroll
  for (int j = 0; j < 8; ++j) {
    int ee = myTe[j];
    int r = run[ee]++;
    rankA[t * 8 + j] = r;
    if (r < CAP) srcTok[ee * CAP + r] = (t * 8 + j) >> 1;
  }
  if (t < 8) {
    unsigned tt[4] = {tot.x, tot.y, tot.z, tot.w};
    counts[t] = (tt[t >> 1] >> ((t & 1) * 16)) & 0xffff;
  }
}

// ---------------- gather x rows into bf16 buf[E][CAP][HD], zero pad ----------------
__global__ __launch_bounds__(128)
void gather_kernel(const float* __restrict__ x, const int* __restrict__ srcTok,
                   const int* __restrict__ counts, unsigned short* __restrict__ buf) {
  int row = blockIdx.x;
  int e = row >> 10;
  int c = row & (CAP - 1);
  int t = threadIdx.x;
  unsigned short* dst = buf + (size_t)row * HD + t * 8;
  if (c < counts[e]) {
    const float* src = x + (size_t)srcTok[row] * HD + t * 8;
    f32x4 v0 = *(const f32x4*)src;
    f32x4 v1 = *(const f32x4*)(src + 4);
    u32x4 o;
    o.x = f2bf(v0.x) | ((unsigned)f2bf(v0.y) << 16);
    o.y = f2bf(v0.z) | ((unsigned)f2bf(v0.w) << 16);
    o.z = f2bf(v1.x) | ((unsigned)f2bf(v1.y) << 16);
    o.w = f2bf(v1.z) | ((unsigned)f2bf(v1.w) << 16);
    *(u32x4*)dst = o;
  } else {
    u32x4 z = {0, 0, 0, 0};
    *(u32x4*)dst = z;
  }
}

// ---------------- 256x256 8-phase double-buffered batched GEMM (m201 template) -------
// A[e][CAP][KTOT] bf16 row-major, Bt[e][NDIM][KTOT] bf16 row-major (= B^T).
// C = A @ Bt^T. 8 waves (2M x 4N), per-wave 128x64, BK=64, 2 K-tile LDS dbuf (128KB).
// 4 phases per K-tile, one half-tile staged per phase, vmcnt(6) once per K-tile.
template <int KTOT, int NDIM, int DO_GELU, int KSPLIT>
__global__ __launch_bounds__(512, 2)
void gemm256(const unsigned short* __restrict__ Ab, const unsigned short* __restrict__ Bb,
             void* __restrict__ Cv) {
  constexpr int KLOC = KTOT / KSPLIT;
  constexpr int NT = KLOC / 64;              // K-tiles
  constexpr int GX = CAP / 256;
  constexpr int GY = NDIM / 256;
  constexpr int NWG = GX * GY * NE * KSPLIT;
  __shared__ char smem[131072];              // 2 bufs x (A 32KB + B 32KB)

  int orig = blockIdx.x;
  int wg = (orig & 7) * (NWG / 8) + (orig >> 3);   // XCD-aware, NWG%8==0
  int bx = wg % GX;
  int by = (wg / GX) % GY;
  int zz = wg / (GX * GY);
  int ks = zz % KSPLIT;
  int e  = zz / KSPLIT;

  const unsigned short* A  = Ab + (size_t)e * CAP * KTOT;
  const unsigned short* Bt = Bb + (size_t)e * NDIM * KTOT;
  int bm = bx * 256, bn = by * 256;
  int kbase = ks * KLOC;

  int tid = threadIdx.x;
  int lane = tid & 63;
  int w = tid >> 6;
  int wr = w >> 2, wc = w & 3;
  int l15 = lane & 15, lq = lane >> 4;

  // ds_read offsets: swizzled granule = (ks*4+lq) ^ (row&7); row&7 == l15&7 always.
  unsigned sw0 = (unsigned)((lq ^ (l15 & 7)) * 16);
  unsigned sw1 = (unsigned)(((4 + lq) ^ (l15 & 7)) * 16);
  // A region: half = m>>2 ; byte = half*16384 + (wr*64 + (m&3)*16 + l15)*128 + sw
  unsigned aBase = (unsigned)((wr * 64 + l15) * 128);
  // B region: half = n>>1 ; byte = 32768 + half*16384 + (wc*32 + (n&1)*16 + l15)*128 + sw
  unsigned bBase = 32768u + (unsigned)((wc * 32 + l15) * 128);

  // staging sources: one half-tile (128 rows x 64 cols) = 2 x 16B per thread.
  // A half h covers rows {h*64..h*64+63} + {128+h*64..}, B half h covers 32-row stripes.
  const char* sA[2][2];
  const char* sB[2][2];
  unsigned dAo[2][2], dBo[2][2];
#pragma unroll
  for (int h = 0; h < 2; ++h)
#pragma unroll
    for (int j = 0; j < 2; ++j) {
      int blk = j * 512 + tid;
      int rl = blk >> 3, s = blk & 7;
      int g = s ^ (rl & 7);                           // swizzle involution on source
      int rowA = ((rl >> 6) << 7) + h * 64 + (rl & 63);
      int rowB = ((rl >> 5) << 6) + h * 32 + (rl & 31);
      sA[h][j] = (const char*)(A  + (size_t)(bm + rowA) * KTOT + kbase + g * 8);
      sB[h][j] = (const char*)(Bt + (size_t)(bn + rowB) * KTOT + kbase + g * 8);
      dAo[h][j] = (unsigned)(h * 16384 + blk * 16);
      dBo[h][j] = (unsigned)(32768 + h * 16384 + blk * 16);
    }

#define STAGE_A(h, dbase, kt) { \
    load_lds16(sA[h][0] + (size_t)(kt) * 128, smem + (dbase) + dAo[h][0]); \
    load_lds16(sA[h][1] + (size_t)(kt) * 128, smem + (dbase) + dAo[h][1]); }
#define STAGE_B(h, dbase, kt) { \
    load_lds16(sB[h][0] + (size_t)(kt) * 128, smem + (dbase) + dBo[h][0]); \
    load_lds16(sB[h][1] + (size_t)(kt) * 128, smem + (dbase) + dBo[h][1]); }

  // prologue: tile0 (4 halves) -> buf0, tile1 (3 halves) -> buf1; A-hi(t1) comes at t0.p0
  STAGE_A(0, 0, 0); STAGE_B(0, 0, 0); STAGE_B(1, 0, 0); STAGE_A(1, 0, 0);
  STAGE_A(0, 65536, 1); STAGE_B(0, 65536, 1); STAGE_B(1, 65536, 1);
  asm volatile("s_waitcnt vmcnt(6)" ::: "memory");
  __builtin_amdgcn_s_barrier();

  f32x4 acc[8][4] = {};
  short8 af[4][2], bl[2][2], bh[2][2];

  for (int t = 0; t < NT; ++t) {
    unsigned cb = (t & 1) ? 65536u : 0u;
    unsigned nb = cb ^ 65536u;
    int kt1 = (t + 1 < NT) ? t + 1 : 0;   // wrapped: keeps vmcnt counting uniform
    int kt2 = (t + 2 < NT) ? t + 2 : 0;

    // ---- phase 0: read A-lo + B-lo (12 reads); stage A-hi of t+1; MFMA (m0-3, n0-1)
#pragma unroll
    for (int m = 0; m < 4; ++m) {
      af[m][0] = *(const short8*)(smem + cb + aBase + m * 2048 + sw0);
      af[m][1] = *(const short8*)(smem + cb + aBase + m * 2048 + sw1);
    }
#pragma unroll
    for (int n = 0; n < 2; ++n) {
      bl[n][0] = *(const short8*)(smem + cb + bBase + n * 2048 + sw0);
      bl[n][1] = *(const short8*)(smem + cb + bBase + n * 2048 + sw1);
    }
    STAGE_A(1, nb, kt1);
    __builtin_amdgcn_s_barrier();
    asm volatile("s_waitcnt lgkmcnt(0)" ::: "memory");
    __builtin_amdgcn_sched_barrier(0);
    __builtin_amdgcn_s_setprio(1);
#pragma unroll
    for (int k2 = 0; k2 < 2; ++k2)
#pragma unroll
      for (int m = 0; m < 4; ++m)
#pragma unroll
        for (int n = 0; n < 2; ++n)
          acc[m][n] = __builtin_amdgcn_mfma_f32_16x16x32_bf16(af[m][k2], bl[n][k2], acc[m][n], 0, 0, 0);
    __builtin_amdgcn_s_setprio(0);
    __builtin_amdgcn_sched_barrier(0);
    __builtin_amdgcn_s_barrier();

    // ---- phase 1: read B-hi (4 reads); stage A-lo of t+2 (into cb); MFMA (m0-3, n2-3)
#pragma unroll
    for (int n = 0; n < 2; ++n) {
      bh[n][0] = *(const short8*)(smem + cb + bBase + 16384 + n * 2048 + sw0);
      bh[n][1] = *(const short8*)(smem + cb + bBase + 16384 + n * 2048 + sw1);
    }
    STAGE_A(0, cb, kt2);
    __builtin_amdgcn_s_barrier();
    asm volatile("s_waitcnt lgkmcnt(0)" ::: "memory");
    __builtin_amdgcn_sched_barrier(0);
    __builtin_amdgcn_s_setprio(1);
#pragma unroll
    for (int k2 = 0; k2 < 2; ++k2)
#pragma unroll
      for (int m = 0; m < 4; ++m)
#pragma unroll
        for (int n = 0; n < 2; ++n)
          acc[m][n + 2] = __builtin_amdgcn_mfma_f32_16x16x32_bf16(af[m][k2], bh[n][k2], acc[m][n + 2], 0, 0, 0);
    __builtin_amdgcn_s_setprio(0);
    __builtin_amdgcn_sched_barrier(0);
    __builtin_amdgcn_s_barrier();

    // ---- phase 2: read A-hi (8 reads); stage B-lo of t+2; MFMA (m4-7, n2-3)
#pragma unroll
    for (int m = 0; m < 4; ++m) {
      af[m][0] = *(const short8*)(smem + cb + aBase + 16384 + m * 2048 + sw0);
      af[m][1] = *(const short8*)(smem + cb + aBase + 16384 + m * 2048 + sw1);
    }
    STAGE_B(0, cb, kt2);
    __builtin_amdgcn_s_barrier();
    asm volatile("s_waitcnt lgkmcnt(0)" ::: "memory");
    __builtin_amdgcn_sched_barrier(0);
    __builtin_amdgcn_s_setprio(1);
#pragma unroll
    for (int k2 = 0; k2 < 2; ++k2)
#pragma unroll
      for (int m = 0; m < 4; ++m)
#pragma unroll
        for (int n = 0; n < 2; ++n)
          acc[m + 4][n + 2] = __builtin_amdgcn_mfma_f32_16x16x32_bf16(af[m][k2], bh[n][k2], acc[m + 4][n + 2], 0, 0, 0);
    __builtin_amdgcn_s_setprio(0);
    __builtin_amdgcn_sched_barrier(0);
    __builtin_amdgcn_s_barrier();

    // ---- phase 3: no reads; stage B-hi of t+2; MFMA (m4-7, n0-1); vmcnt(6) per K-tile
    STAGE_B(1, cb, kt2);
    __builtin_amdgcn_s_barrier();
    __builtin_amdgcn_s_setprio(1);
#pragma unroll
    for (int k2 = 0; k2 < 2; ++k2)
#pragma unroll
      for (int m = 0; m < 4; ++m)
#pragma unroll
        for (int n = 0; n < 2; ++n)
          acc[m + 4][n] = __builtin_amdgcn_mfma_f32_16x16x32_bf16(af[m][k2], bl[n][k2], acc[m + 4][n], 0, 0, 0);
    __builtin_amdgcn_s_setprio(0);
    __builtin_amdgcn_sched_barrier(0);
    asm volatile("s_waitcnt vmcnt(6)" ::: "memory");
    __builtin_amdgcn_s_barrier();
  }
#undef STAGE_A
#undef STAGE_B

  // epilogue
  int r0 = bm + wr * 128 + lq * 4;
  int c0 = bn + wc * 64 + l15;
  if (DO_GELU) {
    unsigned short* C = (unsigned short*)Cv + (size_t)e * CAP * NDIM;
#pragma unroll
    for (int m = 0; m < 8; ++m)
#pragma unroll
      for (int n = 0; n < 4; ++n)
#pragma unroll
        for (int j = 0; j < 4; ++j) {
          float v = acc[m][n][j];
          float y = 0.7978845608028654f * (v + 0.044715f * v * v * v);
          float g = v / (1.0f + __expf(-2.0f * y));   // tanh-gelu
          C[(size_t)(r0 + m * 16 + j) * NDIM + (c0 + n * 16)] = f2bf(g);
        }
  } else {
    float* C = (float*)Cv + ((size_t)ks * NE + e) * CAP * NDIM;
#pragma unroll
    for (int m = 0; m < 8; ++m)
#pragma unroll
      for (int n = 0; n < 4; ++n)
#pragma unroll
        for (int j = 0; j < 4; ++j)
          C[(size_t)(r0 + m * 16 + j) * NDIM + (c0 + n * 16)] = acc[m][n][j];
  }
}

// ---------------- scatter: out[t] = sum_k w[t,k]*(y0[e,r]+y1[e,r]) + bias ----------------
__global__ __launch_bounds__(128)
void scatter_kernel(const float* __restrict__ y, const int* __restrict__ te,
                    const int* __restrict__ rankA, const float* __restrict__ ew,
                    const float* __restrict__ bias, float* __restrict__ out) {
  int tk = blockIdx.x;
  int t = threadIdx.x;
  f32x4 a0 = *(const f32x4*)(bias + t * 8);
  f32x4 a1 = *(const f32x4*)(bias + t * 8 + 4);
#pragma unroll
  for (int k = 0; k < TOPK; ++k) {
    int a = tk * TOPK + k;
    int r = rankA[a];
    if (r < CAP) {
      float wgt = ew[a];
      size_t rowoff = ((size_t)te[a] * CAP + r) * HD + t * 8;
      const float* y0 = y + rowoff;
      const float* y1 = y + (size_t)NE * CAP * HD + rowoff;
      f32x4 v0 = *(const f32x4*)y0 + *(const f32x4*)y1;
      f32x4 v1 = *(const f32x4*)(y0 + 4) + *(const f32x4*)(y1 + 4);
      a0 += wgt * v0;
      a1 += wgt * v1;
    }
  }
  float* o = out + (size_t)tk * HD + t * 8;
  *(f32x4*)o = a0;
  *(f32x4*)(o + 4) = a1;
}

extern "C" void kernel_launch(void* const* d_in, const int* in_sizes, int n_in,
                              void* d_out, int out_size, void* d_ws, size_t ws_size,
                              hipStream_t stream) {
  const float* x    = (const float*)d_in[0];
  const float* ew   = (const float*)d_in[2];
  const int*   te   = (const int*)d_in[3];
  const float* w1   = (const float*)d_in[4];
  const float* w2   = (const float*)d_in[5];
  const float* bias = (const float*)d_in[6];
  float* out = (float*)d_out;

  unsigned short* w1t  = (unsigned short*)d_ws;                 // [E][F][H] bf16  64MB
  unsigned short* w2t  = w1t + (size_t)NE * HD * FD;            // [E][H][F] bf16  64MB
  unsigned short* bufg = w2t + (size_t)NE * HD * FD;            // [E][CAP][H]     16MB
  unsigned short* hbuf = bufg + (size_t)NE * CAP * HD;          // [E][CAP][F]     64MB
  float*          ybuf = (float*)w1t;                           // alias: [2][E][CAP][H] f32 64MB
  int* rankA  = (int*)(hbuf + (size_t)NE * CAP * FD);
  int* srcTok = rankA + NASSIGN;
  int* counts = srcTok + NE * CAP;

  transpose_convert<<<dim3(FD / 64, HD / 64, NE), 256, 0, stream>>>(w1, w1t, HD, FD);
  transpose_convert<<<dim3(HD / 64, FD / 64, NE), 256, 0, stream>>>(w2, w2t, FD, HD);
  routing_kernel<<<1, 1024, 0, stream>>>(te, rankA, srcTok, counts);
  gather_kernel<<<NE * CAP, 128, 0, stream>>>(x, srcTok, counts, bufg);
  // GEMM1: [CAP,HD] @ [FD,HD]^T -> gelu -> bf16 hbuf ; 512 blocks
  gemm256<HD, FD, 1, 1><<<512, 512, 0, stream>>>(bufg, w1t, (void*)hbuf);
  // GEMM2: [CAP,FD] @ [HD,FD]^T -> fp32 partials (split-K=2) ; 256 blocks
  gemm256<FD, HD, 0, 2><<<256, 512, 0, stream>>>(hbuf, w2t, (void*)ybuf);
  scatter_kernel<<<NTOK, 128, 0, stream>>>(ybuf, te, rankA, ew, bias, out);
}